// Round 5
// baseline (34.657 us; speedup 1.0000x reference)
//
#include <hip/hip_runtime.h>

#define SPATIAL_SCALE 0.0625f
#define TRANS_STD 0.1f
#define POOLED 7
#define PART 7
#define NSAMPLE 4

__device__ __forceinline__ unsigned short f2bf(float f) {
  unsigned int u = __float_as_uint(f);
  u = (u + 0x7fffu + ((u >> 16) & 1u)) >> 16;  // round-to-nearest-even
  return (unsigned short)u;
}

// ---------------------------------------------------------------------------
// Kernel 1: NCHW f32 -> NHWC bf16 (per batch: (C, HW) -> (HW, C))
// ---------------------------------------------------------------------------
__global__ __launch_bounds__(256) void transpose_nchw_nhwc_bf16(
    const float* __restrict__ in, unsigned short* __restrict__ out,
    int C, int HW) {
  __shared__ unsigned int tile[32][18];  // [channel][pixel_pair]
  const int b  = blockIdx.z;
  const int p0 = blockIdx.x * 32;
  const int c0 = blockIdx.y * 32;
  const int tx = threadIdx.x;  // 0..7
  const int ty = threadIdx.y;  // 0..31
  const float* src = in + (size_t)b * C * HW;
  unsigned short* dst = out + (size_t)b * HW * C;

  const float4 v = *(const float4*)(src + (size_t)(c0 + ty) * HW + p0 + tx * 4);
  tile[ty][2 * tx]     = (unsigned int)f2bf(v.x) | ((unsigned int)f2bf(v.y) << 16);
  tile[ty][2 * tx + 1] = (unsigned int)f2bf(v.z) | ((unsigned int)f2bf(v.w) << 16);
  __syncthreads();

  const int half = ty & 1;
  unsigned short h[4];
#pragma unroll
  for (int k = 0; k < 4; ++k) {
    const unsigned int w = tile[4 * tx + k][ty >> 1];
    h[k] = half ? (unsigned short)(w >> 16) : (unsigned short)(w & 0xffffu);
  }
  uint2 o;
  o.x = (unsigned int)h[0] | ((unsigned int)h[1] << 16);
  o.y = (unsigned int)h[2] | ((unsigned int)h[3] << 16);
  *(uint2*)(dst + (size_t)(p0 + ty) * C + c0 + tx * 4) = o;
}

// ---------------------------------------------------------------------------
// Shared per-bin geometry (wave-uniform)
// ---------------------------------------------------------------------------
__device__ __forceinline__ void bin_geometry(
    const float* __restrict__ rois, const float* __restrict__ offs,
    int n, int ph, int pw, int H, int W,
    int& b, float& wstart, float& hstart, float& sub_w, float& sub_h) {
  const float r0 = rois[n * 5 + 0];
  const float x1 = rintf(rois[n * 5 + 1]) * SPATIAL_SCALE - 0.5f;
  const float y1 = rintf(rois[n * 5 + 2]) * SPATIAL_SCALE - 0.5f;
  const float x2 = (rintf(rois[n * 5 + 3]) + 1.0f) * SPATIAL_SCALE - 0.5f;
  const float y2 = (rintf(rois[n * 5 + 4]) + 1.0f) * SPATIAL_SCALE - 0.5f;
  const float roi_w = fmaxf(x2 - x1, 0.1f);
  const float roi_h = fmaxf(y2 - y1, 0.1f);
  const float bin_w = roi_w / (float)POOLED;
  const float bin_h = roi_h / (float)POOLED;
  sub_w = bin_w / (float)NSAMPLE;
  sub_h = bin_h / (float)NSAMPLE;
  const int pidx_w = (int)floorf((float)pw / (float)POOLED * (float)PART);
  const int pidx_h = (int)floorf((float)ph / (float)POOLED * (float)PART);
  const float tx = offs[((n * 2 + 0) * PART + pidx_h) * PART + pidx_w] * TRANS_STD;
  const float ty = offs[((n * 2 + 1) * PART + pidx_h) * PART + pidx_w] * TRANS_STD;
  wstart = (float)pw * bin_w + x1 + tx * roi_w;
  hstart = (float)ph * bin_h + y1 + ty * roi_h;
  b = (int)r0;
}

// ---------------------------------------------------------------------------
// Kernel 2: gather from bf16 NHWC. 4 waves/block = 4 bins.
// All 36 loads issued up-front (uint2 v[6][6], static idx) -> 1 vmcnt wait.
// Rows clamped to y1m (dup-line L1 hits); cols x0..x0+5 via compile-time
// immediate offsets (zero weights mask unused; over-read stays inside d_ws).
// ---------------------------------------------------------------------------
__global__ __launch_bounds__(256) void psroi_gather_bf16(
    const unsigned short* __restrict__ feat,  // (B, HW, C) bf16
    const float* __restrict__ rois,
    const float* __restrict__ offs,
    float* __restrict__ out) {                // (N, C, 7, 7) f32
  constexpr int C = 256, H = 128, W = 128;
  const int wave = threadIdx.x >> 6;
  const int lane = threadIdx.x & 63;
  const int bin  = blockIdx.x * 4 + wave;
  const int n  = bin / 49;
  const int pp = bin - n * 49;
  const int ph = pp / 7;
  const int pw = pp - ph * 7;

  int b; float wstart, hstart, sub_w, sub_h;
  bin_geometry(rois, offs, n, ph, pw, H, W, b, wstart, hstart, sub_w, sub_h);

  // ---- per-axis sample analysis (wave-uniform) ----
  int xli[NSAMPLE], xhi[NSAMPLE], yli[NSAMPLE], yhi[NSAMPLE];
  float dxv[NSAMPLE], dyv[NSAMPLE];
  bool vx[NSAMPLE], vy[NSAMPLE];
  int x0 = 1 << 28, y0 = 1 << 28, y1m = -1;
  int nvx = 0, nvy = 0;
#pragma unroll
  for (int s = 0; s < NSAMPLE; ++s) {
    const float ww = wstart + (float)s * sub_w;
    vx[s] = (ww >= -0.5f) && (ww <= (float)W - 0.5f);
    const float wc = fminf(fmaxf(ww, 0.0f), (float)W - 1.0f);
    const float fl = floorf(wc);
    xli[s] = (int)fl;
    xhi[s] = (int)ceilf(wc);
    dxv[s] = wc - fl;
    if (vx[s]) { ++nvx; x0 = min(x0, xli[s]); }

    const float hh = hstart + (float)s * sub_h;
    vy[s] = (hh >= -0.5f) && (hh <= (float)H - 0.5f);
    const float hc = fminf(fmaxf(hh, 0.0f), (float)H - 1.0f);
    const float flh = floorf(hc);
    yli[s] = (int)flh;
    yhi[s] = (int)ceilf(hc);
    dyv[s] = hc - flh;
    if (vy[s]) { ++nvy; y0 = min(y0, yli[s]); y1m = max(y1m, yhi[s]); }
  }

  const int c = lane * 4;
  const size_t obase = ((size_t)n * C + c) * 49 + pp;

  if (nvx == 0 || nvy == 0) {
    out[obase]       = 0.0f;
    out[obase + 49]  = 0.0f;
    out[obase + 98]  = 0.0f;
    out[obase + 147] = 0.0f;
    return;  // wave-uniform; no barriers in this kernel
  }

  // ---- issue ALL loads up-front: rows clamped, cols immediate-offset ----
  // one pixel column = C bf16 = C/4 uint2 = 512 bytes  (C/4, NOT C/2!)
  uint2 v[6][6];
#pragma unroll
  for (int i = 0; i < 6; ++i) {
    const int rowp = min(y0 + i, y1m);
    const uint2* rp =
        (const uint2*)(feat + (((size_t)b * H + rowp) * W + x0) * C + c);
#pragma unroll
    for (int j = 0; j < 6; ++j) {
      v[i][j] = rp[j * (C / 4)];  // byte offset j*512: compile-time immediate
    }
  }

  // ---- build per-axis weight histograms (static indices only) ----
  float wx[6] = {0.f, 0.f, 0.f, 0.f, 0.f, 0.f};
  float wy[6] = {0.f, 0.f, 0.f, 0.f, 0.f, 0.f};
#pragma unroll
  for (int s = 0; s < NSAMPLE; ++s) {
    if (vx[s]) {
#pragma unroll
      for (int k = 0; k < 6; ++k) {
        wx[k] += (xli[s] - x0 == k) ? (1.0f - dxv[s]) : 0.0f;
        wx[k] += (xhi[s] - x0 == k) ? dxv[s] : 0.0f;
      }
    }
    if (vy[s]) {
#pragma unroll
      for (int k = 0; k < 6; ++k) {
        wy[k] += (yli[s] - y0 == k) ? (1.0f - dyv[s]) : 0.0f;
        wy[k] += (yhi[s] - y0 == k) ? dyv[s] : 0.0f;
      }
    }
  }
  const float inv = 1.0f / (float)(nvx * nvy);
#pragma unroll
  for (int k = 0; k < 6; ++k) wy[k] *= inv;

  // ---- accumulate ----
  float acc0 = 0.f, acc1 = 0.f, acc2 = 0.f, acc3 = 0.f;
#pragma unroll
  for (int i = 0; i < 6; ++i) {
    const float wyi = wy[i];
#pragma unroll
    for (int j = 0; j < 6; ++j) {
      const float wgt = wyi * wx[j];
      const float f0 = __uint_as_float(v[i][j].x << 16);
      const float f1 = __uint_as_float(v[i][j].x & 0xffff0000u);
      const float f2 = __uint_as_float(v[i][j].y << 16);
      const float f3 = __uint_as_float(v[i][j].y & 0xffff0000u);
      acc0 = fmaf(wgt, f0, acc0);
      acc1 = fmaf(wgt, f1, acc1);
      acc2 = fmaf(wgt, f2, acc2);
      acc3 = fmaf(wgt, f3, acc3);
    }
  }

  out[obase]       = acc0;
  out[obase + 49]  = acc1;
  out[obase + 98]  = acc2;
  out[obase + 147] = acc3;
}

// ---------------------------------------------------------------------------
// Fallback: direct NCHW f32 gather (only if ws too small).
// ---------------------------------------------------------------------------
__global__ __launch_bounds__(256) void psroi_direct(
    const float* __restrict__ inp, const float* __restrict__ rois,
    const float* __restrict__ offs, float* __restrict__ out,
    int total, int C, int H, int W) {
  int idx = blockIdx.x * 256 + threadIdx.x;
  if (idx >= total) return;
  const int pw = idx % 7;
  int t = idx / 7;
  const int ph = t % 7;
  t /= 7;
  const int c = t % C;
  const int n = t / C;

  int b; float wstart, hstart, sub_w, sub_h;
  bin_geometry(rois, offs, n, ph, pw, H, W, b, wstart, hstart, sub_w, sub_h);

  const float* plane = inp + ((size_t)b * C + c) * H * W;

  float acc = 0.f;
  int cnt = 0;
#pragma unroll
  for (int sy = 0; sy < NSAMPLE; ++sy) {
    const float hh = hstart + (float)sy * sub_h;
    const bool vh = (hh >= -0.5f) && (hh <= (float)H - 0.5f);
    const float hc = fminf(fmaxf(hh, 0.0f), (float)H - 1.0f);
    const float yflo = floorf(hc);
    const int yl = (int)yflo;
    const int yh = (int)ceilf(hc);
    const float dy = hc - yflo;
#pragma unroll
    for (int sx = 0; sx < NSAMPLE; ++sx) {
      const float ww = wstart + (float)sx * sub_w;
      const bool valid = vh && (ww >= -0.5f) && (ww <= (float)W - 0.5f);
      if (!valid) continue;
      ++cnt;
      const float wc = fminf(fmaxf(ww, 0.0f), (float)W - 1.0f);
      const float xflo = floorf(wc);
      const int xl = (int)xflo;
      const int xh = (int)ceilf(wc);
      const float dx = wc - xflo;
      const float v11 = plane[yl * W + xl];
      const float v21 = plane[yl * W + xh];
      const float v12 = plane[yh * W + xl];
      const float v22 = plane[yh * W + xh];
      acc += (1.0f - dx) * (1.0f - dy) * v11 + dx * (1.0f - dy) * v21 +
             (1.0f - dx) * dy * v12 + dx * dy * v22;
    }
  }
  out[idx] = (cnt > 0) ? acc / (float)cnt : 0.0f;
}

extern "C" void kernel_launch(void* const* d_in, const int* in_sizes, int n_in,
                              void* d_out, int out_size, void* d_ws, size_t ws_size,
                              hipStream_t stream) {
  const float* inp  = (const float*)d_in[0];
  const float* rois = (const float*)d_in[1];
  const float* offs = (const float*)d_in[2];
  float* out = (float*)d_out;

  const int B = 2, C = 256, H = 128, W = 128;
  const int N = in_sizes[1] / 5;
  const int HW = H * W;

  // need staging + slack for the benign over-read (few KB)
  const size_t need = (size_t)B * HW * C * sizeof(unsigned short) + 4096;
  if (ws_size >= need) {
    dim3 tb(8, 32);
    dim3 tg(HW / 32, C / 32, B);
    transpose_nchw_nhwc_bf16<<<tg, tb, 0, stream>>>(inp, (unsigned short*)d_ws,
                                                    C, HW);
    const int nbins = N * 49;  // 6272, divisible by 4
    psroi_gather_bf16<<<nbins / 4, 256, 0, stream>>>(
        (const unsigned short*)d_ws, rois, offs, out);
  } else {
    const int total = N * C * 49;
    psroi_direct<<<(total + 255) / 256, 256, 0, stream>>>(inp, rois, offs, out,
                                                          total, C, H, W);
  }
}

// Round 6
// 30.973 us; speedup vs baseline: 1.1189x; 1.1189x over previous
//
#include <hip/hip_runtime.h>

#define SPATIAL_SCALE 0.0625f
#define TRANS_STD 0.1f
#define POOLED 7
#define PART 7
#define NSAMPLE 4

__device__ __forceinline__ unsigned short f2bf(float f) {
  unsigned int u = __float_as_uint(f);
  u = (u + 0x7fffu + ((u >> 16) & 1u)) >> 16;  // round-to-nearest-even
  return (unsigned short)u;
}

// ---------------------------------------------------------------------------
// Kernel 1: NCHW f32 -> NHWC bf16 (per batch: (C, HW) -> (HW, C))
// ---------------------------------------------------------------------------
__global__ __launch_bounds__(256) void transpose_nchw_nhwc_bf16(
    const float* __restrict__ in, unsigned short* __restrict__ out,
    int C, int HW) {
  __shared__ unsigned int tile[32][18];  // [channel][pixel_pair]
  const int b  = blockIdx.z;
  const int p0 = blockIdx.x * 32;
  const int c0 = blockIdx.y * 32;
  const int tx = threadIdx.x;  // 0..7
  const int ty = threadIdx.y;  // 0..31
  const float* src = in + (size_t)b * C * HW;
  unsigned short* dst = out + (size_t)b * HW * C;

  const float4 v = *(const float4*)(src + (size_t)(c0 + ty) * HW + p0 + tx * 4);
  tile[ty][2 * tx]     = (unsigned int)f2bf(v.x) | ((unsigned int)f2bf(v.y) << 16);
  tile[ty][2 * tx + 1] = (unsigned int)f2bf(v.z) | ((unsigned int)f2bf(v.w) << 16);
  __syncthreads();

  const int half = ty & 1;
  unsigned short h[4];
#pragma unroll
  for (int k = 0; k < 4; ++k) {
    const unsigned int w = tile[4 * tx + k][ty >> 1];
    h[k] = half ? (unsigned short)(w >> 16) : (unsigned short)(w & 0xffffu);
  }
  uint2 o;
  o.x = (unsigned int)h[0] | ((unsigned int)h[1] << 16);
  o.y = (unsigned int)h[2] | ((unsigned int)h[3] << 16);
  *(uint2*)(dst + (size_t)(p0 + ty) * C + c0 + tx * 4) = o;
}

// ---------------------------------------------------------------------------
// Shared per-bin geometry (wave-uniform)
// ---------------------------------------------------------------------------
__device__ __forceinline__ void bin_geometry(
    const float* __restrict__ rois, const float* __restrict__ offs,
    int n, int ph, int pw, int H, int W,
    int& b, float& wstart, float& hstart, float& sub_w, float& sub_h) {
  const float r0 = rois[n * 5 + 0];
  const float x1 = rintf(rois[n * 5 + 1]) * SPATIAL_SCALE - 0.5f;
  const float y1 = rintf(rois[n * 5 + 2]) * SPATIAL_SCALE - 0.5f;
  const float x2 = (rintf(rois[n * 5 + 3]) + 1.0f) * SPATIAL_SCALE - 0.5f;
  const float y2 = (rintf(rois[n * 5 + 4]) + 1.0f) * SPATIAL_SCALE - 0.5f;
  const float roi_w = fmaxf(x2 - x1, 0.1f);
  const float roi_h = fmaxf(y2 - y1, 0.1f);
  const float bin_w = roi_w / (float)POOLED;
  const float bin_h = roi_h / (float)POOLED;
  sub_w = bin_w / (float)NSAMPLE;
  sub_h = bin_h / (float)NSAMPLE;
  const int pidx_w = (int)floorf((float)pw / (float)POOLED * (float)PART);
  const int pidx_h = (int)floorf((float)ph / (float)POOLED * (float)PART);
  const float tx = offs[((n * 2 + 0) * PART + pidx_h) * PART + pidx_w] * TRANS_STD;
  const float ty = offs[((n * 2 + 1) * PART + pidx_h) * PART + pidx_w] * TRANS_STD;
  wstart = (float)pw * bin_w + x1 + tx * roi_w;
  hstart = (float)ph * bin_h + y1 + ty * roi_h;
  b = (int)r0;
}

// ---------------------------------------------------------------------------
// Kernel 2: gather from bf16 NHWC. 512-thread block = 8 waves = 8 bins.
// Gather phase identical to R3 (coalesced uint2 loads). Results staged in
// LDS [8][260] then stored c-major/bin-minor: 8x 32B segments per wave-store
// instead of 256x 4B scattered lines (the store-scatter fix).
// ---------------------------------------------------------------------------
__global__ __launch_bounds__(512) void psroi_gather_bf16(
    const unsigned short* __restrict__ feat,  // (B, HW, C) bf16
    const float* __restrict__ rois,
    const float* __restrict__ offs,
    float* __restrict__ out) {                // (N, C, 7, 7) f32
  constexpr int C = 256, H = 128, W = 128;
  constexpr int LSTR = 260;                   // LDS row stride (dwords)
  __shared__ float lds[8 * LSTR];

  const int wave = threadIdx.x >> 6;
  const int lane = threadIdx.x & 63;
  const int gbin = blockIdx.x * 8 + wave;     // 784 blocks * 8 = 6272 exact
  const int n  = gbin / 49;
  const int pp = gbin - n * 49;
  const int ph = pp / 7;
  const int pw = pp - ph * 7;

  int b; float wstart, hstart, sub_w, sub_h;
  bin_geometry(rois, offs, n, ph, pw, H, W, b, wstart, hstart, sub_w, sub_h);

  // ---- per-axis sample analysis (wave-uniform) ----
  int xli[NSAMPLE], xhi[NSAMPLE], yli[NSAMPLE], yhi[NSAMPLE];
  float dxv[NSAMPLE], dyv[NSAMPLE];
  bool vx[NSAMPLE], vy[NSAMPLE];
  int x0 = 1 << 28, y0 = 1 << 28, y1m = -1;
  int nvx = 0, nvy = 0;
#pragma unroll
  for (int s = 0; s < NSAMPLE; ++s) {
    const float ww = wstart + (float)s * sub_w;
    vx[s] = (ww >= -0.5f) && (ww <= (float)W - 0.5f);
    const float wc = fminf(fmaxf(ww, 0.0f), (float)W - 1.0f);
    const float fl = floorf(wc);
    xli[s] = (int)fl;
    xhi[s] = (int)ceilf(wc);
    dxv[s] = wc - fl;
    if (vx[s]) { ++nvx; x0 = min(x0, xli[s]); }

    const float hh = hstart + (float)s * sub_h;
    vy[s] = (hh >= -0.5f) && (hh <= (float)H - 0.5f);
    const float hc = fminf(fmaxf(hh, 0.0f), (float)H - 1.0f);
    const float flh = floorf(hc);
    yli[s] = (int)flh;
    yhi[s] = (int)ceilf(hc);
    dyv[s] = hc - flh;
    if (vy[s]) { ++nvy; y0 = min(y0, yli[s]); y1m = max(y1m, yhi[s]); }
  }

  const bool bin_valid = (nvx > 0) && (nvy > 0);
  // invalid bins: zero weights + safe coords; NO early return (barrier below)
  if (!bin_valid) { x0 = 0; y0 = 0; y1m = 0; }

  // ---- build per-axis weight histograms (static indices only) ----
  float wx[6] = {0.f, 0.f, 0.f, 0.f, 0.f, 0.f};
  float wy[6] = {0.f, 0.f, 0.f, 0.f, 0.f, 0.f};
  if (bin_valid) {
#pragma unroll
    for (int s = 0; s < NSAMPLE; ++s) {
      if (vx[s]) {
#pragma unroll
        for (int k = 0; k < 6; ++k) {
          wx[k] += (xli[s] - x0 == k) ? (1.0f - dxv[s]) : 0.0f;
          wx[k] += (xhi[s] - x0 == k) ? dxv[s] : 0.0f;
        }
      }
      if (vy[s]) {
#pragma unroll
        for (int k = 0; k < 6; ++k) {
          wy[k] += (yli[s] - y0 == k) ? (1.0f - dyv[s]) : 0.0f;
          wy[k] += (yhi[s] - y0 == k) ? dyv[s] : 0.0f;
        }
      }
    }
    const float inv = 1.0f / (float)(nvx * nvy);
#pragma unroll
    for (int k = 0; k < 6; ++k) wy[k] *= inv;
  }

  // ---- accumulate: 6 rows (clamped to y1m), 6 clamped columns each ----
  const int c = lane * 4;
  const unsigned short* fb = feat + (size_t)b * H * W * C + c;
  float acc0 = 0.f, acc1 = 0.f, acc2 = 0.f, acc3 = 0.f;
#pragma unroll
  for (int i = 0; i < 6; ++i) {
    const int rowp = min(y0 + i, y1m);
    const unsigned short* rb = fb + (size_t)(rowp * W) * C;
    uint2 v[6];
#pragma unroll
    for (int j = 0; j < 6; ++j) {
      const int col = min(x0 + j, W - 1);
      v[j] = *(const uint2*)(rb + (size_t)col * C);
    }
    const float wyi = wy[i];
#pragma unroll
    for (int j = 0; j < 6; ++j) {
      const float wgt = wyi * wx[j];
      acc0 = fmaf(wgt, __uint_as_float(v[j].x << 16), acc0);
      acc1 = fmaf(wgt, __uint_as_float(v[j].x & 0xffff0000u), acc1);
      acc2 = fmaf(wgt, __uint_as_float(v[j].y << 16), acc2);
      acc3 = fmaf(wgt, __uint_as_float(v[j].y & 0xffff0000u), acc3);
    }
  }

  // ---- stage into LDS: row = wave(bin), col = channel ----
  *(float4*)&lds[wave * LSTR + c] = make_float4(acc0, acc1, acc2, acc3);
  __syncthreads();

  // ---- coalesced store: lanes = (c-major, bin-minor) ----
  // o in [0, 2048): c = o>>3, bl = o&7 -> 8 consecutive pp per 8 lanes
#pragma unroll
  for (int it = 0; it < 4; ++it) {
    const int o  = it * 512 + threadIdx.x;
    const int cc = o >> 3;
    const int bl = o & 7;
    const int gb2 = blockIdx.x * 8 + bl;
    const int n2  = gb2 / 49;
    const int pp2 = gb2 - n2 * 49;
    out[((size_t)n2 * C + cc) * 49 + pp2] = lds[bl * LSTR + cc];
  }
}

// ---------------------------------------------------------------------------
// Fallback: direct NCHW f32 gather (only if ws too small).
// ---------------------------------------------------------------------------
__global__ __launch_bounds__(256) void psroi_direct(
    const float* __restrict__ inp, const float* __restrict__ rois,
    const float* __restrict__ offs, float* __restrict__ out,
    int total, int C, int H, int W) {
  int idx = blockIdx.x * 256 + threadIdx.x;
  if (idx >= total) return;
  const int pw = idx % 7;
  int t = idx / 7;
  const int ph = t % 7;
  t /= 7;
  const int c = t % C;
  const int n = t / C;

  int b; float wstart, hstart, sub_w, sub_h;
  bin_geometry(rois, offs, n, ph, pw, H, W, b, wstart, hstart, sub_w, sub_h);

  const float* plane = inp + ((size_t)b * C + c) * H * W;

  float acc = 0.f;
  int cnt = 0;
#pragma unroll
  for (int sy = 0; sy < NSAMPLE; ++sy) {
    const float hh = hstart + (float)sy * sub_h;
    const bool vh = (hh >= -0.5f) && (hh <= (float)H - 0.5f);
    const float hc = fminf(fmaxf(hh, 0.0f), (float)H - 1.0f);
    const float yflo = floorf(hc);
    const int yl = (int)yflo;
    const int yh = (int)ceilf(hc);
    const float dy = hc - yflo;
#pragma unroll
    for (int sx = 0; sx < NSAMPLE; ++sx) {
      const float ww = wstart + (float)sx * sub_w;
      const bool valid = vh && (ww >= -0.5f) && (ww <= (float)W - 0.5f);
      if (!valid) continue;
      ++cnt;
      const float wc = fminf(fmaxf(ww, 0.0f), (float)W - 1.0f);
      const float xflo = floorf(wc);
      const int xl = (int)xflo;
      const int xh = (int)ceilf(wc);
      const float dx = wc - xflo;
      const float v11 = plane[yl * W + xl];
      const float v21 = plane[yl * W + xh];
      const float v12 = plane[yh * W + xl];
      const float v22 = plane[yh * W + xh];
      acc += (1.0f - dx) * (1.0f - dy) * v11 + dx * (1.0f - dy) * v21 +
             (1.0f - dx) * dy * v12 + dx * dy * v22;
    }
  }
  out[idx] = (cnt > 0) ? acc / (float)cnt : 0.0f;
}

extern "C" void kernel_launch(void* const* d_in, const int* in_sizes, int n_in,
                              void* d_out, int out_size, void* d_ws, size_t ws_size,
                              hipStream_t stream) {
  const float* inp  = (const float*)d_in[0];
  const float* rois = (const float*)d_in[1];
  const float* offs = (const float*)d_in[2];
  float* out = (float*)d_out;

  const int B = 2, C = 256, H = 128, W = 128;
  const int N = in_sizes[1] / 5;
  const int HW = H * W;

  const size_t need = (size_t)B * HW * C * sizeof(unsigned short);
  if (ws_size >= need) {
    dim3 tb(8, 32);
    dim3 tg(HW / 32, C / 32, B);
    transpose_nchw_nhwc_bf16<<<tg, tb, 0, stream>>>(inp, (unsigned short*)d_ws,
                                                    C, HW);
    const int nbins = N * 49;  // 6272 = 784 blocks * 8 bins
    psroi_gather_bf16<<<nbins / 8, 512, 0, stream>>>(
        (const unsigned short*)d_ws, rois, offs, out);
  } else {
    const int total = N * C * 49;
    psroi_direct<<<(total + 255) / 256, 256, 0, stream>>>(inp, rois, offs, out,
                                                          total, C, H, W);
  }
}